// Round 1
// baseline (701.932 us; speedup 1.0000x reference)
//
#include <hip/hip_runtime.h>
#include <math.h>

#define DIM 4096
#define NH 32
#define NKV 8
#define HD 128
#define WINDOW 4096
#define BATCH 32
#define QKV_N 6144
#define ATTN_SCALE 0.08838834764831845f

__device__ __forceinline__ float4 f4max(float4 a, float4 b) {
  return make_float4(fmaxf(a.x, b.x), fmaxf(a.y, b.y), fmaxf(a.z, b.z), fmaxf(a.w, b.w));
}
__device__ __forceinline__ float4 f4add(float4 a, float4 b) {
  return make_float4(a.x + b.x, a.y + b.y, a.z + b.z, a.w + b.w);
}
__device__ __forceinline__ void fma4(float4& a, float4 x, float4 y) {
  a.x = fmaf(x.x, y.x, a.x); a.y = fmaf(x.y, y.y, a.y);
  a.z = fmaf(x.z, y.z, a.z); a.w = fmaf(x.w, y.w, a.w);
}
__device__ __forceinline__ void fma4s(float4& a, float s, float4 v) {
  a.x = fmaf(s, v.x, a.x); a.y = fmaf(s, v.y, a.y);
  a.z = fmaf(s, v.z, a.z); a.w = fmaf(s, v.w, a.w);
}

// ---------------------------------------------------------------------------
// GEMM partials: part[(slice*32 + r)*N + c] = sum_{k in slice} x[r][k]*w[k][c]
// M = 32 rows fixed. grid = (N/64, 4). block = 256.
// thread: 4 consecutive cols (float4 of w), 2 rows.
// ---------------------------------------------------------------------------
template<int N, int K>
__global__ __launch_bounds__(256)
void gemm_part(const float* __restrict__ x, const float* __restrict__ w,
               float* __restrict__ part) {
  const int t = threadIdx.x;
  const int c0 = blockIdx.x * 64 + (t & 15) * 4;
  const int r0 = (t >> 4) * 2;
  const int kn = K / 4;
  const int ks = blockIdx.y * kn;

  float a00 = 0.f, a01 = 0.f, a02 = 0.f, a03 = 0.f;
  float a10 = 0.f, a11 = 0.f, a12 = 0.f, a13 = 0.f;

  const float* xr0 = x + (size_t)r0 * K;
  const float* xr1 = xr0 + K;
  const float* wp = w + (size_t)ks * N + c0;

  for (int k = ks; k < ks + kn; k += 4) {
    float4 xa = *(const float4*)(xr0 + k);
    float4 xb = *(const float4*)(xr1 + k);
    float xav[4] = {xa.x, xa.y, xa.z, xa.w};
    float xbv[4] = {xb.x, xb.y, xb.z, xb.w};
#pragma unroll
    for (int kk = 0; kk < 4; ++kk) {
      float4 wv = *(const float4*)(wp);
      wp += N;
      a00 = fmaf(xav[kk], wv.x, a00);
      a01 = fmaf(xav[kk], wv.y, a01);
      a02 = fmaf(xav[kk], wv.z, a02);
      a03 = fmaf(xav[kk], wv.w, a03);
      a10 = fmaf(xbv[kk], wv.x, a10);
      a11 = fmaf(xbv[kk], wv.y, a11);
      a12 = fmaf(xbv[kk], wv.z, a12);
      a13 = fmaf(xbv[kk], wv.w, a13);
    }
  }
  float* p = part + ((size_t)blockIdx.y * 32 + r0) * N + c0;
  *(float4*)p = make_float4(a00, a01, a02, a03);
  *(float4*)(p + N) = make_float4(a10, a11, a12, a13);
}

// ---------------------------------------------------------------------------
// Reduce the 4 K-slices of the qkv GEMM, apply RoPE to q and k sections,
// scatter to q / k_new / v_new. idx over 32 rows x 48 heads x 64 d-pairs.
// ---------------------------------------------------------------------------
__global__ __launch_bounds__(256)
void rope_reduce(const float* __restrict__ part, const float* __restrict__ cosv,
                 const float* __restrict__ sinv, float* __restrict__ q,
                 float* __restrict__ knew, float* __restrict__ vnew) {
  int idx = blockIdx.x * 256 + threadIdx.x;   // < 32*48*64 = 98304
  int r = idx / 3072;
  int rem = idx - r * 3072;
  int head = rem >> 6;     // 0..47  (0..31 q, 32..39 k, 40..47 v)
  int d = rem & 63;
  int c1 = head * 128 + d;
  int c2 = c1 + 64;
  float v1 = 0.f, v2 = 0.f;
#pragma unroll
  for (int s = 0; s < 4; ++s) {
    v1 += part[((size_t)s * 32 + r) * QKV_N + c1];
    v2 += part[((size_t)s * 32 + r) * QKV_N + c2];
  }
  if (head < NH + NKV) {
    float c_lo = cosv[d], c_hi = cosv[d + 64];
    float s_lo = sinv[d], s_hi = sinv[d + 64];
    float o1 = v1 * c_lo - v2 * s_lo;     // d < 64:  t*cos - t[d+64]*sin
    float o2 = v2 * c_hi + v1 * s_hi;     // d >= 64: t*cos + t[d-64]*sin
    if (head < NH) {
      q[((size_t)r * NH + head) * HD + d] = o1;
      q[((size_t)r * NH + head) * HD + d + 64] = o2;
    } else {
      int g = head - NH;
      knew[((size_t)r * NKV + g) * HD + d] = o1;
      knew[((size_t)r * NKV + g) * HD + d + 64] = o2;
    }
  } else {
    int g = head - NH - NKV;
    vnew[((size_t)r * NKV + g) * HD + d] = v1;
    vnew[((size_t)r * NKV + g) * HD + d + 64] = v2;
  }
}

// ---------------------------------------------------------------------------
// Attention: one block per (b, g). 512 threads.
// Phase 1: scores[t][h] = scale * q[h].k[t] + mask   (4 lanes per position)
// Phase 2: softmax over t (block reduce max, exp, block reduce sum)
// Phase 3: out[h][d] = sum_t P[t][h] * v[t][d] / sum  (cooperative over V rows)
// Position cur uses k_new / v_new instead of the (unmodified) cache.
// ---------------------------------------------------------------------------
__global__ __launch_bounds__(512)
void attn_kernel(const float* __restrict__ q, const float* __restrict__ knew,
                 const float* __restrict__ vnew, const float* __restrict__ cache_k,
                 const float* __restrict__ cache_v, const float* __restrict__ mask,
                 const int* __restrict__ start_pos_p, float* __restrict__ scores,
                 float* __restrict__ attn_out) {
  const int b = blockIdx.x >> 3;
  const int g = blockIdx.x & 7;
  const int t = threadIdx.x;
  const int sp = start_pos_p[0];
  const int cur = sp & (WINDOW - 1);
  int plen = ((sp + 1 + 31) >> 5) << 5;
  if (plen > WINDOW) plen = WINDOW;

  __shared__ float q_s[4][HD];        // 2 KB
  __shared__ float4 red4[512];        // 8 KB
  __shared__ float pv[16][4][HD];     // 32 KB

  // load q for the 4 heads of this kv-group
  if (t < 512) {
    int h = t >> 7, d = t & 127;
    q_s[h][d] = q[((size_t)b * NH + (g * 4 + h)) * HD + d];
  }
  __syncthreads();

  const size_t bg = (size_t)b * NKV + g;
  const float* kbase = cache_k + bg * WINDOW * HD;
  const float* vbase = cache_v + bg * WINDOW * HD;
  const float* krow_new = knew + bg * HD;
  const float* vrow_new = vnew + bg * HD;
  float* sc = scores + (size_t)blockIdx.x * WINDOW * 4;

  // ---- Phase 1: scores ----
  {
    const int p0 = t >> 2;   // 0..127 position lane
    const int dl = t & 3;    // which quarter of head_dim
    for (int tt = p0; tt < plen; tt += 128) {
      const float* krow = (tt == cur) ? krow_new : (kbase + (size_t)tt * HD);
      float4 acc0 = {0, 0, 0, 0}, acc1 = {0, 0, 0, 0}, acc2 = {0, 0, 0, 0}, acc3 = {0, 0, 0, 0};
#pragma unroll
      for (int j = 0; j < 8; ++j) {
        const int f = dl + 4 * j;            // float4 index into the 128 dims
        float4 kv = *(const float4*)(krow + 4 * f);
        fma4(acc0, kv, *(const float4*)(&q_s[0][4 * f]));
        fma4(acc1, kv, *(const float4*)(&q_s[1][4 * f]));
        fma4(acc2, kv, *(const float4*)(&q_s[2][4 * f]));
        fma4(acc3, kv, *(const float4*)(&q_s[3][4 * f]));
      }
      float s0 = acc0.x + acc0.y + acc0.z + acc0.w;
      float s1 = acc1.x + acc1.y + acc1.z + acc1.w;
      float s2 = acc2.x + acc2.y + acc2.z + acc2.w;
      float s3 = acc3.x + acc3.y + acc3.z + acc3.w;
      s0 += __shfl_xor(s0, 1); s0 += __shfl_xor(s0, 2);
      s1 += __shfl_xor(s1, 1); s1 += __shfl_xor(s1, 2);
      s2 += __shfl_xor(s2, 1); s2 += __shfl_xor(s2, 2);
      s3 += __shfl_xor(s3, 1); s3 += __shfl_xor(s3, 2);
      float sv = (dl == 0) ? s0 : (dl == 1) ? s1 : (dl == 2) ? s2 : s3;
      sv = sv * ATTN_SCALE + mask[(size_t)b * WINDOW + tt];
      sc[(size_t)tt * 4 + dl] = sv;
    }
  }
  __threadfence();
  __syncthreads();

  // ---- Phase 2a: max per head ----
  float4 lmax = {-1e30f, -1e30f, -1e30f, -1e30f};
  for (int tt = t; tt < plen; tt += 512) {
    lmax = f4max(lmax, *(const float4*)(sc + (size_t)tt * 4));
  }
  red4[t] = lmax;
  __syncthreads();
  for (int s = 256; s > 0; s >>= 1) {
    if (t < s) red4[t] = f4max(red4[t], red4[t + s]);
    __syncthreads();
  }
  float4 mx = red4[0];
  __syncthreads();

  // ---- Phase 2b: exp + sum ----
  float4 lsum = {0, 0, 0, 0};
  for (int tt = t; tt < plen; tt += 512) {
    float4 s = *(const float4*)(sc + (size_t)tt * 4);
    s.x = __expf(s.x - mx.x);
    s.y = __expf(s.y - mx.y);
    s.z = __expf(s.z - mx.z);
    s.w = __expf(s.w - mx.w);
    *(float4*)(sc + (size_t)tt * 4) = s;
    lsum = f4add(lsum, s);
  }
  __threadfence();
  red4[t] = lsum;
  __syncthreads();
  for (int s = 256; s > 0; s >>= 1) {
    if (t < s) red4[t] = f4add(red4[t], red4[t + s]);
    __syncthreads();
  }
  float4 sum = red4[0];
  float4 inv = make_float4(1.f / sum.x, 1.f / sum.y, 1.f / sum.z, 1.f / sum.w);
  __syncthreads();

  // ---- Phase 3: PV, cooperative over V rows ----
  {
    const int d4 = t & 31;       // float4 index over the 128 dims
    const int toff = t >> 5;     // 0..15
    float4 acc0 = {0, 0, 0, 0}, acc1 = {0, 0, 0, 0}, acc2 = {0, 0, 0, 0}, acc3 = {0, 0, 0, 0};
    for (int tt = toff; tt < plen; tt += 16) {
      const float* vrow = (tt == cur) ? vrow_new : (vbase + (size_t)tt * HD);
      float4 vv = *(const float4*)(vrow + 4 * d4);
      float4 p = *(const float4*)(sc + (size_t)tt * 4);
      fma4s(acc0, p.x, vv);
      fma4s(acc1, p.y, vv);
      fma4s(acc2, p.z, vv);
      fma4s(acc3, p.w, vv);
    }
    *(float4*)(&pv[toff][0][4 * d4]) = acc0;
    *(float4*)(&pv[toff][1][4 * d4]) = acc1;
    *(float4*)(&pv[toff][2][4 * d4]) = acc2;
    *(float4*)(&pv[toff][3][4 * d4]) = acc3;
  }
  __syncthreads();
  {
    int h = t >> 7, d = t & 127;
    float s = 0.f;
#pragma unroll
    for (int o = 0; o < 16; ++o) s += pv[o][h][d];
    float invh = (h == 0) ? inv.x : (h == 1) ? inv.y : (h == 2) ? inv.z : inv.w;
    attn_out[(size_t)b * DIM + (size_t)(g * 4 + h) * HD + d] = s * invh;
  }
}

// ---------------------------------------------------------------------------
// Final reduce of wo GEMM partials -> d_out
// ---------------------------------------------------------------------------
__global__ __launch_bounds__(256)
void reduce_out(const float* __restrict__ part, float* __restrict__ out) {
  int idx = blockIdx.x * 256 + threadIdx.x;   // < 32*4096
  float s = 0.f;
#pragma unroll
  for (int sl = 0; sl < 4; ++sl) s += part[(size_t)sl * 32 * DIM + idx];
  out[idx] = s;
}

extern "C" void kernel_launch(void* const* d_in, const int* in_sizes, int n_in,
                              void* d_out, int out_size, void* d_ws, size_t ws_size,
                              hipStream_t stream) {
  const float* x       = (const float*)d_in[0];
  const float* wqkv    = (const float*)d_in[1];
  const float* wo      = (const float*)d_in[2];
  const float* cosv    = (const float*)d_in[3];
  const float* sinv    = (const float*)d_in[4];
  const float* cache_k = (const float*)d_in[5];
  const float* cache_v = (const float*)d_in[6];
  const float* mask    = (const float*)d_in[7];
  const int*   start_p = (const int*)d_in[8];
  float* ws = (float*)d_ws;

  // region1 (16 MB): qkv partials (12 MB) -> scores (16 MB) -> wo partials (2 MB)
  float* part     = ws;
  float* scores   = ws;
  float* q        = ws + 4194304;
  float* knew     = q + 131072;
  float* vnew     = knew + 32768;
  float* attn_out = vnew + 32768;
  float* out      = (float*)d_out;

  gemm_part<QKV_N, DIM><<<dim3(QKV_N / 64, 4), 256, 0, stream>>>(x, wqkv, part);
  rope_reduce<<<384, 256, 0, stream>>>(part, cosv, sinv, q, knew, vnew);
  attn_kernel<<<BATCH * NKV, 512, 0, stream>>>(q, knew, vnew, cache_k, cache_v,
                                               mask, start_p, scores, attn_out);
  gemm_part<DIM, DIM><<<dim3(DIM / 64, 4), 256, 0, stream>>>(attn_out, wo, part);
  reduce_out<<<(BATCH * DIM) / 256, 256, 0, stream>>>(part, out);
}

// Round 2
// 368.068 us; speedup vs baseline: 1.9071x; 1.9071x over previous
//
#include <hip/hip_runtime.h>
#include <math.h>

#define DIM 4096
#define NH 32
#define NKV 8
#define HD 128
#define WINDOW 4096
#define BATCH 32
#define QKV_N 6144
#define ATTN_SCALE 0.08838834764831845f
#define CHUNK 512
#define NC 8          // WINDOW / CHUNK
#define SLICES 8      // GEMM K-split

__device__ __forceinline__ float4 f4max(float4 a, float4 b) {
  return make_float4(fmaxf(a.x, b.x), fmaxf(a.y, b.y), fmaxf(a.z, b.z), fmaxf(a.w, b.w));
}
__device__ __forceinline__ float4 f4add(float4 a, float4 b) {
  return make_float4(a.x + b.x, a.y + b.y, a.z + b.z, a.w + b.w);
}
__device__ __forceinline__ void fma4(float4& a, float4 x, float4 y) {
  a.x = fmaf(x.x, y.x, a.x); a.y = fmaf(x.y, y.y, a.y);
  a.z = fmaf(x.z, y.z, a.z); a.w = fmaf(x.w, y.w, a.w);
}
__device__ __forceinline__ void fma4s(float4& a, float s, float4 v) {
  a.x = fmaf(s, v.x, a.x); a.y = fmaf(s, v.y, a.y);
  a.z = fmaf(s, v.z, a.z); a.w = fmaf(s, v.w, a.w);
}

// ---------------------------------------------------------------------------
// GEMM partials: part[(slice*32 + r)*N + c] = sum_{k in slice} x[r][k]*w[k][c]
// grid = (N/64, NS). block = 256. thread: 4 cols (float4 of w), 2 rows.
// ---------------------------------------------------------------------------
template<int N, int K, int NS>
__global__ __launch_bounds__(256)
void gemm_part(const float* __restrict__ x, const float* __restrict__ w,
               float* __restrict__ part) {
  const int t = threadIdx.x;
  const int c0 = blockIdx.x * 64 + (t & 15) * 4;
  const int r0 = (t >> 4) * 2;
  const int kn = K / NS;
  const int ks = blockIdx.y * kn;

  float a00 = 0.f, a01 = 0.f, a02 = 0.f, a03 = 0.f;
  float a10 = 0.f, a11 = 0.f, a12 = 0.f, a13 = 0.f;

  const float* xr0 = x + (size_t)r0 * K;
  const float* xr1 = xr0 + K;
  const float* wp = w + (size_t)ks * N + c0;

  for (int k = ks; k < ks + kn; k += 4) {
    float4 xa = *(const float4*)(xr0 + k);
    float4 xb = *(const float4*)(xr1 + k);
    float xav[4] = {xa.x, xa.y, xa.z, xa.w};
    float xbv[4] = {xb.x, xb.y, xb.z, xb.w};
#pragma unroll
    for (int kk = 0; kk < 4; ++kk) {
      float4 wv = *(const float4*)(wp);
      wp += N;
      a00 = fmaf(xav[kk], wv.x, a00);
      a01 = fmaf(xav[kk], wv.y, a01);
      a02 = fmaf(xav[kk], wv.z, a02);
      a03 = fmaf(xav[kk], wv.w, a03);
      a10 = fmaf(xbv[kk], wv.x, a10);
      a11 = fmaf(xbv[kk], wv.y, a11);
      a12 = fmaf(xbv[kk], wv.z, a12);
      a13 = fmaf(xbv[kk], wv.w, a13);
    }
  }
  float* p = part + ((size_t)blockIdx.y * 32 + r0) * N + c0;
  *(float4*)p = make_float4(a00, a01, a02, a03);
  *(float4*)(p + N) = make_float4(a10, a11, a12, a13);
}

// ---------------------------------------------------------------------------
// Reduce the SLICES K-slices of the qkv GEMM, apply RoPE, scatter q/knew/vnew.
// ---------------------------------------------------------------------------
__global__ __launch_bounds__(256)
void rope_reduce(const float* __restrict__ part, const float* __restrict__ cosv,
                 const float* __restrict__ sinv, float* __restrict__ q,
                 float* __restrict__ knew, float* __restrict__ vnew) {
  int idx = blockIdx.x * 256 + threadIdx.x;   // < 32*48*64 = 98304
  int r = idx / 3072;
  int rem = idx - r * 3072;
  int head = rem >> 6;     // 0..47  (0..31 q, 32..39 k, 40..47 v)
  int d = rem & 63;
  int c1 = head * 128 + d;
  int c2 = c1 + 64;
  float v1 = 0.f, v2 = 0.f;
#pragma unroll
  for (int s = 0; s < SLICES; ++s) {
    v1 += part[((size_t)s * 32 + r) * QKV_N + c1];
    v2 += part[((size_t)s * 32 + r) * QKV_N + c2];
  }
  if (head < NH + NKV) {
    float c_lo = cosv[d], c_hi = cosv[d + 64];
    float s_lo = sinv[d], s_hi = sinv[d + 64];
    float o1 = v1 * c_lo - v2 * s_lo;
    float o2 = v2 * c_hi + v1 * s_hi;
    if (head < NH) {
      q[((size_t)r * NH + head) * HD + d] = o1;
      q[((size_t)r * NH + head) * HD + d + 64] = o2;
    } else {
      int g = head - NH;
      knew[((size_t)r * NKV + g) * HD + d] = o1;
      knew[((size_t)r * NKV + g) * HD + d + 64] = o2;
    }
  } else {
    int g = head - NH - NKV;
    vnew[((size_t)r * NKV + g) * HD + d] = v1;
    vnew[((size_t)r * NKV + g) * HD + d + 64] = v2;
  }
}

// ---------------------------------------------------------------------------
// Flash-decode chunk: grid (256 bg, NC chunks), 256 threads.
// Per chunk: scores (LDS) -> local softmax (m, s) -> partial PV.
// Emits pvp[c][bg][h][d] and msp[c][bg][h][{m,s}].
// ---------------------------------------------------------------------------
__global__ __launch_bounds__(256)
void attn_chunk(const float* __restrict__ q, const float* __restrict__ knew,
                const float* __restrict__ vnew, const float* __restrict__ cache_k,
                const float* __restrict__ cache_v, const float* __restrict__ mask,
                const int* __restrict__ start_pos_p,
                float* __restrict__ pvp, float* __restrict__ msp) {
  const int bg = blockIdx.x;            // b*NKV + g
  const int b = bg >> 3;
  const int c = blockIdx.y;
  const int t = threadIdx.x;
  const int sp = start_pos_p[0];
  const int cur = sp & (WINDOW - 1);
  int plen = ((sp + 1 + 31) >> 5) << 5;
  if (plen > WINDOW) plen = WINDOW;
  const int t0 = c * CHUNK;
  const int tend = min(t0 + CHUNK, plen);

  const size_t msbase = (((size_t)c * 256 + bg) * 4) * 2;
  float* pvb = pvp + (((size_t)c * 256 + bg) * 4) * HD;

  __shared__ __align__(16) float q_s[4][HD];      // 2 KB
  __shared__ __align__(16) float s_lds[CHUNK][4]; // 8 KB
  __shared__ float4 scratch4[1024];               // 16 KB: red4 / pv partial
  float* scratch = (float*)scratch4;

  if (t0 >= plen) {   // inactive chunk: neutral partials
    if (t < 8) msp[msbase + t] = (t & 1) ? 0.f : -1e30f;
    for (int i = t; i < 4 * HD; i += 256) pvb[i] = 0.f;
    return;
  }

  for (int i = t; i < 512; i += 256) {
    int h = i >> 7, d = i & 127;
    q_s[h][d] = q[((size_t)b * NH + ((bg & 7) * 4 + h)) * HD + d];
  }
  __syncthreads();

  const float* kbase = cache_k + (size_t)bg * WINDOW * HD;
  const float* vbase = cache_v + (size_t)bg * WINDOW * HD;
  const float* krow_new = knew + (size_t)bg * HD;
  const float* vrow_new = vnew + (size_t)bg * HD;

  // ---- Phase 1: scores into LDS ----
  {
    const int p0 = t >> 2;   // 0..63
    const int dl = t & 3;
    for (int tt = t0 + p0; tt < t0 + CHUNK; tt += 64) {
      if (tt < tend) {
        const float* krow = (tt == cur) ? krow_new : (kbase + (size_t)tt * HD);
        float4 a0 = {0,0,0,0}, a1 = {0,0,0,0}, a2 = {0,0,0,0}, a3 = {0,0,0,0};
#pragma unroll
        for (int j = 0; j < 8; ++j) {
          const int f = dl + 4 * j;
          float4 kv = *(const float4*)(krow + 4 * f);
          fma4(a0, kv, *(const float4*)(&q_s[0][4 * f]));
          fma4(a1, kv, *(const float4*)(&q_s[1][4 * f]));
          fma4(a2, kv, *(const float4*)(&q_s[2][4 * f]));
          fma4(a3, kv, *(const float4*)(&q_s[3][4 * f]));
        }
        float s0 = a0.x + a0.y + a0.z + a0.w;
        float s1 = a1.x + a1.y + a1.z + a1.w;
        float s2 = a2.x + a2.y + a2.z + a2.w;
        float s3 = a3.x + a3.y + a3.z + a3.w;
        s0 += __shfl_xor(s0, 1); s0 += __shfl_xor(s0, 2);
        s1 += __shfl_xor(s1, 1); s1 += __shfl_xor(s1, 2);
        s2 += __shfl_xor(s2, 1); s2 += __shfl_xor(s2, 2);
        s3 += __shfl_xor(s3, 1); s3 += __shfl_xor(s3, 2);
        float sv = (dl == 0) ? s0 : (dl == 1) ? s1 : (dl == 2) ? s2 : s3;
        s_lds[tt - t0][dl] = sv * ATTN_SCALE + mask[(size_t)b * WINDOW + tt];
      } else {
        s_lds[tt - t0][dl] = -1e30f;
      }
    }
  }
  __syncthreads();

  // ---- Phase 2: local softmax (max, exp, sum); keep raw sum ----
  float4* red4 = scratch4;
  float4 lmax = {-1e30f, -1e30f, -1e30f, -1e30f};
  for (int i = t; i < CHUNK; i += 256) lmax = f4max(lmax, *(const float4*)(s_lds[i]));
  red4[t] = lmax;
  __syncthreads();
  for (int s = 128; s > 0; s >>= 1) {
    if (t < s) red4[t] = f4max(red4[t], red4[t + s]);
    __syncthreads();
  }
  float4 mx = red4[0];
  __syncthreads();

  float4 lsum = {0, 0, 0, 0};
  for (int i = t; i < CHUNK; i += 256) {
    float4 s = *(const float4*)(s_lds[i]);
    s.x = __expf(s.x - mx.x);
    s.y = __expf(s.y - mx.y);
    s.z = __expf(s.z - mx.z);
    s.w = __expf(s.w - mx.w);
    *(float4*)(s_lds[i]) = s;
    lsum = f4add(lsum, s);
  }
  red4[t] = lsum;
  __syncthreads();
  for (int s = 128; s > 0; s >>= 1) {
    if (t < s) red4[t] = f4add(red4[t], red4[t + s]);
    __syncthreads();
  }
  if (t == 0) {
    float4 sm = red4[0];
    msp[msbase + 0] = mx.x; msp[msbase + 1] = sm.x;
    msp[msbase + 2] = mx.y; msp[msbase + 3] = sm.y;
    msp[msbase + 4] = mx.z; msp[msbase + 5] = sm.z;
    msp[msbase + 6] = mx.w; msp[msbase + 7] = sm.w;
  }
  __syncthreads();   // scratch about to be reused

  // ---- Phase 3: partial PV ----
  {
    const int d4 = t & 31;
    const int toff = t >> 5;   // 0..7
    float4 a0 = {0,0,0,0}, a1 = {0,0,0,0}, a2 = {0,0,0,0}, a3 = {0,0,0,0};
    for (int tt = t0 + toff; tt < tend; tt += 8) {
      const float* vrow = (tt == cur) ? vrow_new : (vbase + (size_t)tt * HD);
      float4 vv = *(const float4*)(vrow + 4 * d4);
      float4 p = *(const float4*)(s_lds[tt - t0]);
      fma4s(a0, p.x, vv);
      fma4s(a1, p.y, vv);
      fma4s(a2, p.z, vv);
      fma4s(a3, p.w, vv);
    }
    *(float4*)(&scratch[(toff * 4 + 0) * HD + 4 * d4]) = a0;
    *(float4*)(&scratch[(toff * 4 + 1) * HD + 4 * d4]) = a1;
    *(float4*)(&scratch[(toff * 4 + 2) * HD + 4 * d4]) = a2;
    *(float4*)(&scratch[(toff * 4 + 3) * HD + 4 * d4]) = a3;
  }
  __syncthreads();
  for (int i = t; i < 4 * HD; i += 256) {
    float s = 0.f;
#pragma unroll
    for (int o = 0; o < 8; ++o) s += scratch[o * 512 + i];
    pvb[i] = s;
  }
}

// ---------------------------------------------------------------------------
// Combine chunk partials: exact LSE merge over NC chunks.
// ---------------------------------------------------------------------------
__global__ __launch_bounds__(256)
void attn_combine(const float* __restrict__ pvp, const float* __restrict__ msp,
                  float* __restrict__ attn_out) {
  int idx = blockIdx.x * 256 + threadIdx.x;   // < 32*4096
  int b = idx >> 12;
  int rem = idx & 4095;
  int hf = rem >> 7;    // 0..31
  int d = rem & 127;
  int g = hf >> 2, hh = hf & 3;
  int bg = b * 8 + g;
  float mv[NC], sv[NC];
  float M = -1e30f;
#pragma unroll
  for (int c = 0; c < NC; ++c) {
    mv[c] = msp[(((size_t)c * 256 + bg) * 4 + hh) * 2];
    sv[c] = msp[(((size_t)c * 256 + bg) * 4 + hh) * 2 + 1];
    M = fmaxf(M, mv[c]);
  }
  float num = 0.f, den = 0.f;
#pragma unroll
  for (int c = 0; c < NC; ++c) {
    float w = __expf(mv[c] - M);
    den = fmaf(sv[c], w, den);
    num = fmaf(pvp[(((size_t)c * 256 + bg) * 4 + hh) * HD + d], w, num);
  }
  attn_out[idx] = num / den;
}

// ---------------------------------------------------------------------------
// Final reduce of wo GEMM partials -> d_out
// ---------------------------------------------------------------------------
__global__ __launch_bounds__(256)
void reduce_out(const float* __restrict__ part, float* __restrict__ out) {
  int idx = blockIdx.x * 256 + threadIdx.x;   // < 32*4096
  float s = 0.f;
#pragma unroll
  for (int sl = 0; sl < SLICES; ++sl) s += part[(size_t)sl * 32 * DIM + idx];
  out[idx] = s;
}

extern "C" void kernel_launch(void* const* d_in, const int* in_sizes, int n_in,
                              void* d_out, int out_size, void* d_ws, size_t ws_size,
                              hipStream_t stream) {
  const float* x       = (const float*)d_in[0];
  const float* wqkv    = (const float*)d_in[1];
  const float* wo      = (const float*)d_in[2];
  const float* cosv    = (const float*)d_in[3];
  const float* sinv    = (const float*)d_in[4];
  const float* cache_k = (const float*)d_in[5];
  const float* cache_v = (const float*)d_in[6];
  const float* mask    = (const float*)d_in[7];
  const int*   start_p = (const int*)d_in[8];
  float* ws = (float*)d_ws;

  float* part     = ws;                      // SLICES*32*6144 = 1,572,864 floats
  float* q        = ws + 1572864;            // 131072
  float* knew     = q + 131072;              // 32768
  float* vnew     = knew + 32768;            // 32768
  float* attn_out = vnew + 32768;            // 131072
  float* pvp      = attn_out + 131072;       // NC*256*4*128 = 1,048,576
  float* msp      = pvp + 1048576;           // NC*256*4*2 = 16384
  float* out      = (float*)d_out;

  gemm_part<QKV_N, DIM, SLICES><<<dim3(QKV_N / 64, SLICES), 256, 0, stream>>>(x, wqkv, part);
  rope_reduce<<<384, 256, 0, stream>>>(part, cosv, sinv, q, knew, vnew);
  attn_chunk<<<dim3(BATCH * NKV, NC), 256, 0, stream>>>(q, knew, vnew, cache_k,
                                                        cache_v, mask, start_p,
                                                        pvp, msp);
  attn_combine<<<512, 256, 0, stream>>>(pvp, msp, attn_out);
  gemm_part<DIM, DIM, SLICES><<<dim3(DIM / 64, SLICES), 256, 0, stream>>>(attn_out, wo, part);
  reduce_out<<<512, 256, 0, stream>>>(part, out);
}

// Round 3
// 364.250 us; speedup vs baseline: 1.9271x; 1.0105x over previous
//
#include <hip/hip_runtime.h>
#include <math.h>

#define DIM 4096
#define NH 32
#define NKV 8
#define HD 128
#define WINDOW 4096
#define BATCH 32
#define QKV_N 6144
#define ATTN_SCALE 0.08838834764831845f
#define CHUNK 256
#define NC 16         // WINDOW / CHUNK
#define SLICES 16     // GEMM K-split

__device__ __forceinline__ float4 f4max(float4 a, float4 b) {
  return make_float4(fmaxf(a.x, b.x), fmaxf(a.y, b.y), fmaxf(a.z, b.z), fmaxf(a.w, b.w));
}
__device__ __forceinline__ float4 f4add(float4 a, float4 b) {
  return make_float4(a.x + b.x, a.y + b.y, a.z + b.z, a.w + b.w);
}
__device__ __forceinline__ void fma4(float4& a, float4 x, float4 y) {
  a.x = fmaf(x.x, y.x, a.x); a.y = fmaf(x.y, y.y, a.y);
  a.z = fmaf(x.z, y.z, a.z); a.w = fmaf(x.w, y.w, a.w);
}
__device__ __forceinline__ void fma4s(float4& a, float s, float4 v) {
  a.x = fmaf(s, v.x, a.x); a.y = fmaf(s, v.y, a.y);
  a.z = fmaf(s, v.z, a.z); a.w = fmaf(s, v.w, a.w);
}
__device__ __forceinline__ float4 wred_max(float4 v) {
#pragma unroll
  for (int o = 1; o < 64; o <<= 1) {
    v.x = fmaxf(v.x, __shfl_xor(v.x, o));
    v.y = fmaxf(v.y, __shfl_xor(v.y, o));
    v.z = fmaxf(v.z, __shfl_xor(v.z, o));
    v.w = fmaxf(v.w, __shfl_xor(v.w, o));
  }
  return v;
}
__device__ __forceinline__ float4 wred_add(float4 v) {
#pragma unroll
  for (int o = 1; o < 64; o <<= 1) {
    v.x += __shfl_xor(v.x, o);
    v.y += __shfl_xor(v.y, o);
    v.z += __shfl_xor(v.z, o);
    v.w += __shfl_xor(v.w, o);
  }
  return v;
}

// ---------------------------------------------------------------------------
// GEMM partials: part[(slice*32 + r)*N + c] = sum_{k in slice} x[r][k]*w[k][c]
// grid = (N/64, NS). block = 256. thread: 4 cols (float4 of w), 2 rows.
// ---------------------------------------------------------------------------
template<int N, int K, int NS>
__global__ __launch_bounds__(256)
void gemm_part(const float* __restrict__ x, const float* __restrict__ w,
               float* __restrict__ part) {
  const int t = threadIdx.x;
  const int c0 = blockIdx.x * 64 + (t & 15) * 4;
  const int r0 = (t >> 4) * 2;
  const int kn = K / NS;
  const int ks = blockIdx.y * kn;

  float a00 = 0.f, a01 = 0.f, a02 = 0.f, a03 = 0.f;
  float a10 = 0.f, a11 = 0.f, a12 = 0.f, a13 = 0.f;

  const float* xr0 = x + (size_t)r0 * K;
  const float* xr1 = xr0 + K;
  const float* wp = w + (size_t)ks * N + c0;

  for (int k = ks; k < ks + kn; k += 4) {
    float4 xa = *(const float4*)(xr0 + k);
    float4 xb = *(const float4*)(xr1 + k);
    float xav[4] = {xa.x, xa.y, xa.z, xa.w};
    float xbv[4] = {xb.x, xb.y, xb.z, xb.w};
#pragma unroll
    for (int kk = 0; kk < 4; ++kk) {
      float4 wv = *(const float4*)(wp);
      wp += N;
      a00 = fmaf(xav[kk], wv.x, a00);
      a01 = fmaf(xav[kk], wv.y, a01);
      a02 = fmaf(xav[kk], wv.z, a02);
      a03 = fmaf(xav[kk], wv.w, a03);
      a10 = fmaf(xbv[kk], wv.x, a10);
      a11 = fmaf(xbv[kk], wv.y, a11);
      a12 = fmaf(xbv[kk], wv.z, a12);
      a13 = fmaf(xbv[kk], wv.w, a13);
    }
  }
  float* p = part + ((size_t)blockIdx.y * 32 + r0) * N + c0;
  *(float4*)p = make_float4(a00, a01, a02, a03);
  *(float4*)(p + N) = make_float4(a10, a11, a12, a13);
}

// ---------------------------------------------------------------------------
// Reduce the SLICES K-slices of the qkv GEMM, apply RoPE, scatter q/knew/vnew.
// ---------------------------------------------------------------------------
__global__ __launch_bounds__(256)
void rope_reduce(const float* __restrict__ part, const float* __restrict__ cosv,
                 const float* __restrict__ sinv, float* __restrict__ q,
                 float* __restrict__ knew, float* __restrict__ vnew) {
  int idx = blockIdx.x * 256 + threadIdx.x;   // < 32*48*64 = 98304
  int r = idx / 3072;
  int rem = idx - r * 3072;
  int head = rem >> 6;     // 0..47  (0..31 q, 32..39 k, 40..47 v)
  int d = rem & 63;
  int c1 = head * 128 + d;
  int c2 = c1 + 64;
  float v1 = 0.f, v2 = 0.f;
#pragma unroll
  for (int s = 0; s < SLICES; ++s) {
    v1 += part[((size_t)s * 32 + r) * QKV_N + c1];
    v2 += part[((size_t)s * 32 + r) * QKV_N + c2];
  }
  if (head < NH + NKV) {
    float c_lo = cosv[d], c_hi = cosv[d + 64];
    float s_lo = sinv[d], s_hi = sinv[d + 64];
    float o1 = v1 * c_lo - v2 * s_lo;
    float o2 = v2 * c_hi + v1 * s_hi;
    if (head < NH) {
      q[((size_t)r * NH + head) * HD + d] = o1;
      q[((size_t)r * NH + head) * HD + d + 64] = o2;
    } else {
      int g = head - NH;
      knew[((size_t)r * NKV + g) * HD + d] = o1;
      knew[((size_t)r * NKV + g) * HD + d + 64] = o2;
    }
  } else {
    int g = head - NH - NKV;
    vnew[((size_t)r * NKV + g) * HD + d] = v1;
    vnew[((size_t)r * NKV + g) * HD + d + 64] = v2;
  }
}

// ---------------------------------------------------------------------------
// Flash-decode chunk: grid (256 bg, NC chunks), 256 threads.
// CHUNK == blockDim, so softmax state is thread-local (s_lds[t] owned by t).
// Emits pvp[c][bg][h][d] and msp[c][bg][h][{m,s}].
// ---------------------------------------------------------------------------
__global__ __launch_bounds__(256)
void attn_chunk(const float* __restrict__ q, const float* __restrict__ knew,
                const float* __restrict__ vnew, const float* __restrict__ cache_k,
                const float* __restrict__ cache_v, const float* __restrict__ mask,
                const int* __restrict__ start_pos_p,
                float* __restrict__ pvp, float* __restrict__ msp) {
  const int bg = blockIdx.x;            // b*NKV + g
  const int b = bg >> 3;
  const int c = blockIdx.y;
  const int t = threadIdx.x;
  const int w = t >> 6;                 // wave id 0..3
  const int sp = start_pos_p[0];
  const int cur = sp & (WINDOW - 1);
  int plen = ((sp + 1 + 31) >> 5) << 5;
  if (plen > WINDOW) plen = WINDOW;
  const int t0 = c * CHUNK;
  const int tend = min(t0 + CHUNK, plen);

  const size_t msbase = (((size_t)c * 256 + bg) * 4) * 2;
  float* pvb = pvp + (((size_t)c * 256 + bg) * 4) * HD;

  __shared__ __align__(16) float q_s[4][HD];      // 2 KB
  __shared__ __align__(16) float s_lds[CHUNK][4]; // 4 KB
  __shared__ __align__(16) float4 red_s[8];       // max[0..3], sum[4..7]
  __shared__ __align__(16) float scratch[8 * 512];// 16 KB pv partials

  if (t0 >= plen) {   // inactive chunk: neutral partials
    if (t < 8) msp[msbase + t] = (t & 1) ? 0.f : -1e30f;
    for (int i = t; i < 4 * HD; i += 256) pvb[i] = 0.f;
    return;
  }

  for (int i = t; i < 512; i += 256) {
    int h = i >> 7, d = i & 127;
    q_s[h][d] = q[((size_t)b * NH + ((bg & 7) * 4 + h)) * HD + d];
  }
  __syncthreads();

  const float* kbase = cache_k + (size_t)bg * WINDOW * HD;
  const float* vbase = cache_v + (size_t)bg * WINDOW * HD;
  const float* krow_new = knew + (size_t)bg * HD;
  const float* vrow_new = vnew + (size_t)bg * HD;

  // ---- Phase 1: scores into LDS ----
  {
    const int p0 = t >> 2;   // 0..63
    const int dl = t & 3;
    for (int tt = t0 + p0; tt < t0 + CHUNK; tt += 64) {
      if (tt < tend) {
        const float* krow = (tt == cur) ? krow_new : (kbase + (size_t)tt * HD);
        float4 a0 = {0,0,0,0}, a1 = {0,0,0,0}, a2 = {0,0,0,0}, a3 = {0,0,0,0};
#pragma unroll
        for (int j = 0; j < 8; ++j) {
          const int f = dl + 4 * j;
          float4 kv = *(const float4*)(krow + 4 * f);
          fma4(a0, kv, *(const float4*)(&q_s[0][4 * f]));
          fma4(a1, kv, *(const float4*)(&q_s[1][4 * f]));
          fma4(a2, kv, *(const float4*)(&q_s[2][4 * f]));
          fma4(a3, kv, *(const float4*)(&q_s[3][4 * f]));
        }
        float s0 = a0.x + a0.y + a0.z + a0.w;
        float s1 = a1.x + a1.y + a1.z + a1.w;
        float s2 = a2.x + a2.y + a2.z + a2.w;
        float s3 = a3.x + a3.y + a3.z + a3.w;
        s0 += __shfl_xor(s0, 1); s0 += __shfl_xor(s0, 2);
        s1 += __shfl_xor(s1, 1); s1 += __shfl_xor(s1, 2);
        s2 += __shfl_xor(s2, 1); s2 += __shfl_xor(s2, 2);
        s3 += __shfl_xor(s3, 1); s3 += __shfl_xor(s3, 2);
        float sv = (dl == 0) ? s0 : (dl == 1) ? s1 : (dl == 2) ? s2 : s3;
        s_lds[tt - t0][dl] = sv * ATTN_SCALE + mask[(size_t)b * WINDOW + tt];
      } else {
        s_lds[tt - t0][dl] = -1e30f;
      }
    }
  }
  __syncthreads();

  // ---- Phase 2: softmax; thread t owns row t of s_lds ----
  float4 sval = *(const float4*)(s_lds[t]);
  float4 m = wred_max(sval);
  if ((t & 63) == 0) red_s[w] = m;
  __syncthreads();
  float4 mx = f4max(f4max(red_s[0], red_s[1]), f4max(red_s[2], red_s[3]));

  float4 e;
  e.x = __expf(sval.x - mx.x);
  e.y = __expf(sval.y - mx.y);
  e.z = __expf(sval.z - mx.z);
  e.w = __expf(sval.w - mx.w);
  *(float4*)(s_lds[t]) = e;
  float4 s = wred_add(e);
  if ((t & 63) == 0) red_s[4 + w] = s;
  __syncthreads();   // covers both red_s[4..7] and the exp stores to s_lds
  if (t == 0) {
    float4 sm = f4add(f4add(red_s[4], red_s[5]), f4add(red_s[6], red_s[7]));
    msp[msbase + 0] = mx.x; msp[msbase + 1] = sm.x;
    msp[msbase + 2] = mx.y; msp[msbase + 3] = sm.y;
    msp[msbase + 4] = mx.z; msp[msbase + 5] = sm.z;
    msp[msbase + 6] = mx.w; msp[msbase + 7] = sm.w;
  }

  // ---- Phase 3: partial PV ----
  {
    const int d4 = t & 31;
    const int toff = t >> 5;   // 0..7
    float4 a0 = {0,0,0,0}, a1 = {0,0,0,0}, a2 = {0,0,0,0}, a3 = {0,0,0,0};
    for (int tt = t0 + toff; tt < tend; tt += 8) {
      const float* vrow = (tt == cur) ? vrow_new : (vbase + (size_t)tt * HD);
      float4 vv = *(const float4*)(vrow + 4 * d4);
      float4 p = *(const float4*)(s_lds[tt - t0]);
      fma4s(a0, p.x, vv);
      fma4s(a1, p.y, vv);
      fma4s(a2, p.z, vv);
      fma4s(a3, p.w, vv);
    }
    *(float4*)(&scratch[(toff * 4 + 0) * HD + 4 * d4]) = a0;
    *(float4*)(&scratch[(toff * 4 + 1) * HD + 4 * d4]) = a1;
    *(float4*)(&scratch[(toff * 4 + 2) * HD + 4 * d4]) = a2;
    *(float4*)(&scratch[(toff * 4 + 3) * HD + 4 * d4]) = a3;
  }
  __syncthreads();
  for (int i = t; i < 4 * HD; i += 256) {
    float s2 = 0.f;
#pragma unroll
    for (int o = 0; o < 8; ++o) s2 += scratch[o * 512 + i];
    pvb[i] = s2;
  }
}

// ---------------------------------------------------------------------------
// Combine chunk partials: exact LSE merge over NC chunks.
// ---------------------------------------------------------------------------
__global__ __launch_bounds__(256)
void attn_combine(const float* __restrict__ pvp, const float* __restrict__ msp,
                  float* __restrict__ attn_out) {
  int idx = blockIdx.x * 256 + threadIdx.x;   // < 32*4096
  int b = idx >> 12;
  int rem = idx & 4095;
  int hf = rem >> 7;    // 0..31
  int d = rem & 127;
  int g = hf >> 2, hh = hf & 3;
  int bg = b * 8 + g;
  float mv[NC], sv[NC];
  float M = -1e30f;
#pragma unroll
  for (int c = 0; c < NC; ++c) {
    mv[c] = msp[(((size_t)c * 256 + bg) * 4 + hh) * 2];
    sv[c] = msp[(((size_t)c * 256 + bg) * 4 + hh) * 2 + 1];
    M = fmaxf(M, mv[c]);
  }
  float num = 0.f, den = 0.f;
#pragma unroll
  for (int c = 0; c < NC; ++c) {
    float w = __expf(mv[c] - M);
    den = fmaf(sv[c], w, den);
    num = fmaf(pvp[(((size_t)c * 256 + bg) * 4 + hh) * HD + d], w, num);
  }
  attn_out[idx] = num / den;
}

// ---------------------------------------------------------------------------
// Final reduce of wo GEMM partials -> d_out
// ---------------------------------------------------------------------------
__global__ __launch_bounds__(256)
void reduce_out(const float* __restrict__ part, float* __restrict__ out) {
  int idx = blockIdx.x * 256 + threadIdx.x;   // < 32*4096
  float s = 0.f;
#pragma unroll
  for (int sl = 0; sl < SLICES; ++sl) s += part[(size_t)sl * 32 * DIM + idx];
  out[idx] = s;
}

extern "C" void kernel_launch(void* const* d_in, const int* in_sizes, int n_in,
                              void* d_out, int out_size, void* d_ws, size_t ws_size,
                              hipStream_t stream) {
  const float* x       = (const float*)d_in[0];
  const float* wqkv    = (const float*)d_in[1];
  const float* wo      = (const float*)d_in[2];
  const float* cosv    = (const float*)d_in[3];
  const float* sinv    = (const float*)d_in[4];
  const float* cache_k = (const float*)d_in[5];
  const float* cache_v = (const float*)d_in[6];
  const float* mask    = (const float*)d_in[7];
  const int*   start_p = (const int*)d_in[8];
  float* ws = (float*)d_ws;

  float* part     = ws;                      // SLICES*32*6144 = 3,145,728 floats
  float* q        = ws + 3145728;            // 131072
  float* knew     = q + 131072;              // 32768
  float* vnew     = knew + 32768;            // 32768
  float* attn_out = vnew + 32768;            // 131072
  float* pvp      = attn_out + 131072;       // NC*256*4*128 = 2,097,152
  float* msp      = pvp + 2097152;           // NC*256*4*2 = 32768
  float* out      = (float*)d_out;

  gemm_part<QKV_N, DIM, SLICES><<<dim3(QKV_N / 64, SLICES), 256, 0, stream>>>(x, wqkv, part);
  rope_reduce<<<384, 256, 0, stream>>>(part, cosv, sinv, q, knew, vnew);
  attn_chunk<<<dim3(BATCH * NKV, NC), 256, 0, stream>>>(q, knew, vnew, cache_k,
                                                        cache_v, mask, start_p,
                                                        pvp, msp);
  attn_combine<<<512, 256, 0, stream>>>(pvp, msp, attn_out);
  gemm_part<DIM, DIM, SLICES><<<dim3(DIM / 64, SLICES), 256, 0, stream>>>(attn_out, wo, part);
  reduce_out<<<512, 256, 0, stream>>>(part, out);
}